// Round 1
// baseline (594.265 us; speedup 1.0000x reference)
//
#include <hip/hip_runtime.h>
#include <hip/hip_bf16.h>

// Self-attention block: B=8,C=256,H=W=64 -> N=4096, D=32
//   q=Wq x, k=Wk x, v=Wv x ; P=softmax(q k^T) ; out = Wo (v P^T) * gamma + x
// fp32 throughout (reference is fp32; CDNA4 has no fp32 MFMA -> VALU FMA).
// Pipeline: [qkv_kernel] -> [flash_kernel (key-split partials)] -> [merge_proj_kernel]

#define B_ 8
#define C_ 256
#define N_ 4096
#define D_ 32
#define RPB 256   // rows per flash block (128 thr * 2 rows)
#define TPB2 128

// ---------------- kernel 1: QKV projection -------------------------------
// grid (64 ntiles, 3 mats, 8 batches), 256 threads
// out[mat][b][n][d] = sum_c w[d][c] * x[b][c][n]
__global__ __launch_bounds__(256) void qkv_kernel(
    const float* __restrict__ x, const float* __restrict__ wq,
    const float* __restrict__ wk, const float* __restrict__ wv,
    float* __restrict__ Q, float* __restrict__ Ko, float* __restrict__ Vo)
{
    __shared__ float wls[256][36];  // wls[c][d] (pad 36 keeps float4 16B-aligned)
    const int tid = threadIdx.x;
    const int ntile = blockIdx.x, mat = blockIdx.y, b = blockIdx.z;
    const float* w = (mat == 0) ? wq : (mat == 1 ? wk : wv);
    float* outp    = (mat == 0) ? Q  : (mat == 1 ? Ko : Vo);

    // stage transposed weights: coalesced read, strided LDS write (once)
    #pragma unroll
    for (int k = 0; k < 32; ++k) wls[tid][k] = w[k * 256 + tid];
    __syncthreads();

    const int n  = ntile * 64 + (tid & 63);
    const int d0 = (tid >> 6) * 8;     // 4 groups of 8 d's
    const float* xb = x + (size_t)b * C_ * N_ + n;

    float acc[8];
    #pragma unroll
    for (int j = 0; j < 8; ++j) acc[j] = 0.f;

    float xn = xb[0];
    for (int c = 0; c < 256; ++c) {
        const float xv = xn;
        if (c < 255) xn = xb[(size_t)(c + 1) * N_];   // prefetch next x row
        const float4 wa = *(const float4*)&wls[c][d0];      // broadcast (uniform addr)
        const float4 wb = *(const float4*)&wls[c][d0 + 4];
        acc[0] += wa.x * xv; acc[1] += wa.y * xv; acc[2] += wa.z * xv; acc[3] += wa.w * xv;
        acc[4] += wb.x * xv; acc[5] += wb.y * xv; acc[6] += wb.z * xv; acc[7] += wb.w * xv;
    }
    float* op = outp + ((size_t)b * N_ + n) * D_ + d0;
    *(float4*)op       = make_float4(acc[0], acc[1], acc[2], acc[3]);
    *(float4*)(op + 4) = make_float4(acc[4], acc[5], acc[6], acc[7]);
}

// ---------------- kernel 2: flash attention partials ---------------------
// grid (kcnt, 16 rowblocks, 8 batches), 128 threads, 2 rows/thread.
// Each block: 256 query rows vs one chunk of N/kcnt keys -> partial O,m,l.
__global__ __launch_bounds__(128, 2) void flash_kernel(
    const float* __restrict__ Q, const float* __restrict__ Kg,
    const float* __restrict__ Vg, float* __restrict__ Opart,
    float* __restrict__ Ml, int kch, int ntiles, int kcnt)
{
    __shared__ float4 kbuf[2][512];   // [buf][64 keys * 8 float4]
    __shared__ float4 vbuf[2][512];
    const int tid = threadIdx.x;
    const int kc = blockIdx.x, rb = blockIdx.y, b = blockIdx.z;
    const int r0 = rb * RPB + tid * 2;

    const float4* Qv = (const float4*)(Q + ((size_t)b * N_ + r0) * D_);
    float4 q0[8], q1[8], O0[8], O1[8];
    #pragma unroll
    for (int j = 0; j < 8; ++j) {
        q0[j] = Qv[j]; q1[j] = Qv[8 + j];
        O0[j] = make_float4(0.f, 0.f, 0.f, 0.f); O1[j] = O0[j];
    }
    float m0r = -3e38f, m1r = -3e38f, l0 = 0.f, l1 = 0.f;

    const float4* Kg4 = (const float4*)(Kg + ((size_t)b * N_ + (size_t)kc * kch) * D_);
    const float4* Vg4 = (const float4*)(Vg + ((size_t)b * N_ + (size_t)kc * kch) * D_);

    // prologue: stage tile 0
    #pragma unroll
    for (int j = 0; j < 4; ++j) {
        kbuf[0][tid + j * 128] = Kg4[tid + j * 128];
        vbuf[0][tid + j * 128] = Vg4[tid + j * 128];
    }
    int buf = 0;
    float4 kr[4], vr[4];

    for (int t = 0; t < ntiles; ++t) {
        __syncthreads();   // staged writes to `buf` visible
        if (t < ntiles - 1) {   // issue next-tile loads early (latency hides under compute)
            #pragma unroll
            for (int j = 0; j < 4; ++j) {
                kr[j] = Kg4[(size_t)(t + 1) * 512 + tid + j * 128];
                vr[j] = Vg4[(size_t)(t + 1) * 512 + tid + j * 128];
            }
        }
        for (int m = 0; m < 64; ++m) {
            const float4* kp = &kbuf[buf][m * 8];   // uniform addr -> LDS broadcast
            float a0 = 0, b0 = 0, c0 = 0, e0 = 0, a1 = 0, b1 = 0, c1 = 0, e1 = 0;
            #pragma unroll
            for (int j = 0; j < 8; ++j) {
                const float4 kj = kp[j];
                a0 += q0[j].x * kj.x; b0 += q0[j].y * kj.y;
                c0 += q0[j].z * kj.z; e0 += q0[j].w * kj.w;
                a1 += q1[j].x * kj.x; b1 += q1[j].y * kj.y;
                c1 += q1[j].z * kj.z; e1 += q1[j].w * kj.w;
            }
            const float s0 = (a0 + b0) + (c0 + e0);
            const float s1 = (a1 + b1) + (c1 + e1);
            const float nm0 = fmaxf(m0r, s0), nm1 = fmaxf(m1r, s1);
            if (__any((nm0 > m0r) | (nm1 > m1r))) {   // rare after warm-up, wave-uniform branch
                const float f0 = __expf(m0r - nm0), f1 = __expf(m1r - nm1);
                m0r = nm0; m1r = nm1; l0 *= f0; l1 *= f1;
                #pragma unroll
                for (int j = 0; j < 8; ++j) {
                    O0[j].x *= f0; O0[j].y *= f0; O0[j].z *= f0; O0[j].w *= f0;
                    O1[j].x *= f1; O1[j].y *= f1; O1[j].z *= f1; O1[j].w *= f1;
                }
            }
            const float p0 = __expf(s0 - m0r), p1 = __expf(s1 - m1r);
            l0 += p0; l1 += p1;
            const float4* vp = &vbuf[buf][m * 8];
            #pragma unroll
            for (int j = 0; j < 8; ++j) {
                const float4 vj = vp[j];
                O0[j].x += p0 * vj.x; O0[j].y += p0 * vj.y;
                O0[j].z += p0 * vj.z; O0[j].w += p0 * vj.w;
                O1[j].x += p1 * vj.x; O1[j].y += p1 * vj.y;
                O1[j].z += p1 * vj.z; O1[j].w += p1 * vj.w;
            }
        }
        if (t < ntiles - 1) {   // write-late into the other buffer
            #pragma unroll
            for (int j = 0; j < 4; ++j) {
                kbuf[buf ^ 1][tid + j * 128] = kr[j];
                vbuf[buf ^ 1][tid + j * 128] = vr[j];
            }
        }
        buf ^= 1;
    }

    float4* Op = (float4*)(Opart + (((size_t)b * kcnt + kc) * N_ + r0) * D_);
    #pragma unroll
    for (int j = 0; j < 8; ++j) { Op[j] = O0[j]; Op[8 + j] = O1[j]; }
    float2* mlp = (float2*)(Ml + (((size_t)b * kcnt + kc) * N_ + r0) * 2);
    mlp[0] = make_float2(m0r, l0);
    mlp[1] = make_float2(m1r, l1);
}

// ---------------- kernel 3: merge partials + Wo projection + residual ----
// grid (64 ntiles, 8 batches), 256 threads
__global__ __launch_bounds__(256) void merge_proj_kernel(
    const float* __restrict__ Opart, const float* __restrict__ Ml,
    const float* __restrict__ wo, const float* __restrict__ gamma,
    const float* __restrict__ x, float* __restrict__ out, int kcnt)
{
    __shared__ float oc[64][33];     // combined O rows (pad 33: conflict-free b32)
    __shared__ float wot[32][260];   // wo transposed [d][c] (pad, 16B-aligned rows)
    const int tid = threadIdx.x;
    const int n0 = blockIdx.x * 64, b = blockIdx.y;

    for (int i = tid; i < 256 * 32; i += 256) {   // stage wot[d][c] = wo[c][d]
        const int c = i >> 5, d = i & 31;
        wot[d][c] = wo[i];
    }

    const int nl = tid & 63;
    const int n = n0 + nl;
    const int grp = tid >> 6;   // 0..3

    // phase B: combine partials; group handles d0 = grp*8
    {
        const int d0 = grp * 8;
        float mstar = -3e38f;
        for (int c8 = 0; c8 < kcnt; ++c8) {
            const float2 ml = *(const float2*)(Ml + (((size_t)b * kcnt + c8) * N_ + n) * 2);
            mstar = fmaxf(mstar, ml.x);
        }
        float acc[8];
        #pragma unroll
        for (int j = 0; j < 8; ++j) acc[j] = 0.f;
        float lstar = 0.f;
        for (int c8 = 0; c8 < kcnt; ++c8) {   // reload Ml (L2-hot) to avoid reg-array dyn-index
            const float2 ml = *(const float2*)(Ml + (((size_t)b * kcnt + c8) * N_ + n) * 2);
            const float wgt = __expf(ml.x - mstar);
            lstar += wgt * ml.y;
            const float4* op = (const float4*)(Opart + (((size_t)b * kcnt + c8) * N_ + n) * D_ + d0);
            const float4 o0 = op[0], o1 = op[1];
            acc[0] += wgt * o0.x; acc[1] += wgt * o0.y; acc[2] += wgt * o0.z; acc[3] += wgt * o0.w;
            acc[4] += wgt * o1.x; acc[5] += wgt * o1.y; acc[6] += wgt * o1.z; acc[7] += wgt * o1.w;
        }
        const float inv = 1.0f / lstar;
        #pragma unroll
        for (int j = 0; j < 8; ++j) oc[nl][d0 + j] = acc[j] * inv;
    }
    __syncthreads();

    // phase C: project to C=256 channels, + gamma*o + x
    const float g = gamma[0];
    const float* xb = x + (size_t)b * C_ * N_ + n;
    float* ob = out + (size_t)b * C_ * N_ + n;
    for (int cg = 0; cg < 8; ++cg) {
        const int c0 = grp * 64 + cg * 8;
        float acc8[8];
        #pragma unroll
        for (int j = 0; j < 8; ++j) acc8[j] = 0.f;
        for (int d = 0; d < 32; ++d) {
            const float ov = oc[nl][d];                       // conflict-free (pad 33)
            const float4 w0 = *(const float4*)&wot[d][c0];     // uniform -> broadcast
            const float4 w1 = *(const float4*)&wot[d][c0 + 4];
            acc8[0] += w0.x * ov; acc8[1] += w0.y * ov; acc8[2] += w0.z * ov; acc8[3] += w0.w * ov;
            acc8[4] += w1.x * ov; acc8[5] += w1.y * ov; acc8[6] += w1.z * ov; acc8[7] += w1.w * ov;
        }
        #pragma unroll
        for (int j = 0; j < 8; ++j) {
            const size_t off = (size_t)(c0 + j) * N_;
            ob[off] = g * acc8[j] + xb[off];   // coalesced (lanes = consecutive n)
        }
    }
}

extern "C" void kernel_launch(void* const* d_in, const int* in_sizes, int n_in,
                              void* d_out, int out_size, void* d_ws, size_t ws_size,
                              hipStream_t stream) {
    const float* x  = (const float*)d_in[0];
    const float* wq = (const float*)d_in[1];
    const float* wk = (const float*)d_in[2];
    const float* wv = (const float*)d_in[3];
    const float* wo = (const float*)d_in[4];
    const float* gm = (const float*)d_in[5];
    float* out = (float*)d_out;

    // pick key-split count to fit workspace (deterministic across calls)
    int kcnt = 8;
    while (kcnt > 1) {
        const size_t need = (3 * (size_t)B_ * N_ * D_ +
                             (size_t)B_ * kcnt * N_ * (D_ + 2)) * sizeof(float);
        if (need <= ws_size) break;
        kcnt >>= 1;
    }
    const int kch = N_ / kcnt;        // keys per chunk
    const int ntiles = kch / 64;      // 64-key tiles per chunk

    float* ws = (float*)d_ws;
    float* Q = ws;
    float* K = Q + (size_t)B_ * N_ * D_;
    float* V = K + (size_t)B_ * N_ * D_;
    float* Opart = V + (size_t)B_ * N_ * D_;
    float* Ml = Opart + (size_t)B_ * kcnt * N_ * D_;

    qkv_kernel<<<dim3(64, 3, B_), 256, 0, stream>>>(x, wq, wk, wv, Q, K, V);
    flash_kernel<<<dim3(kcnt, N_ / RPB, B_), TPB2, 0, stream>>>(Q, K, V, Opart, Ml,
                                                                kch, ntiles, kcnt);
    merge_proj_kernel<<<dim3(64, B_), 256, 0, stream>>>(Opart, Ml, wo, gm, x, out, kcnt);
}

// Round 3
// 186.885 us; speedup vs baseline: 3.1799x; 3.1799x over previous
//
#include <hip/hip_runtime.h>
#include <hip/hip_bf16.h>
#include <hip/hip_fp16.h>

// Self-attention B=8,C=256,N=4096,D=32 — fp16 MFMA flash attention.
// qkv (fp32 VALU, fp16 out; V stored transposed+window-permuted) ->
// flash (16x16x32 f16 MFMA, swapped QK^T, no LDS/barriers) -> merge+Wo.

typedef _Float16 f16;
typedef f16 f16x8 __attribute__((ext_vector_type(8)));
typedef __fp16 h16x2 __attribute__((ext_vector_type(2)));   // cvt_pkrtz return type
typedef float f32x4 __attribute__((ext_vector_type(4)));

#define B_ 8
#define C_ 256
#define N_ 4096
#define D_ 32

// ---- kernel 1: QKV projection ------------------------------------------
// grid (64 ntiles, 3 mats, 8 b), 256 thr. out fp16.
// V is written transposed [b][d][col] with per-32-key column permutation so
// flash's PV B-operand (built from S^T output regs) pairs slots correctly.
__global__ __launch_bounds__(256) void qkv_kernel(
    const float* __restrict__ x, const float* __restrict__ wq,
    const float* __restrict__ wk, const float* __restrict__ wv,
    f16* __restrict__ Q, f16* __restrict__ K, f16* __restrict__ Vt)
{
    __shared__ float wls[256][36];
    const int tid = threadIdx.x;
    const int ntile = blockIdx.x, mat = blockIdx.y, b = blockIdx.z;
    const float* w = (mat == 0) ? wq : (mat == 1 ? wk : wv);

    #pragma unroll
    for (int k = 0; k < 32; ++k) wls[tid][k] = w[k * 256 + tid];
    __syncthreads();

    const int n  = ntile * 64 + (tid & 63);
    const int d0 = (tid >> 6) * 8;
    const float* xb = x + (size_t)b * C_ * N_ + n;

    float acc[8];
    #pragma unroll
    for (int j = 0; j < 8; ++j) acc[j] = 0.f;

    float xn = xb[0];
    for (int c = 0; c < 256; ++c) {
        const float xv = xn;
        if (c < 255) xn = xb[(size_t)(c + 1) * N_];
        const float4 wa = *(const float4*)&wls[c][d0];
        const float4 wb = *(const float4*)&wls[c][d0 + 4];
        acc[0] += wa.x * xv; acc[1] += wa.y * xv; acc[2] += wa.z * xv; acc[3] += wa.w * xv;
        acc[4] += wb.x * xv; acc[5] += wb.y * xv; acc[6] += wb.z * xv; acc[7] += wb.w * xv;
    }

    if (mat < 2) {
        f16* op = (mat == 0 ? Q : K) + ((size_t)b * N_ + n) * D_ + d0;
        f16x8 h;
        #pragma unroll
        for (int j = 0; j < 8; ++j) h[j] = (f16)acc[j];
        *(f16x8*)op = h;
    } else {
        // key n -> column c within its 32-key window:
        // c = 8*((n>>2)&3) + 4*((n>>4)&1) + (n&3)  (matches S^T reg ordering)
        const int p = n & 31;
        const int cidx = (n & ~31) + 8 * ((p >> 2) & 3) + 4 * ((p >> 4) & 1) + (p & 3);
        f16* vb = Vt + ((size_t)b * D_ + d0) * N_ + cidx;
        #pragma unroll
        for (int j = 0; j < 8; ++j) vb[(size_t)j * N_] = (f16)acc[j];
    }
}

// ---- kernel 2: fp16 MFMA flash attention -------------------------------
// grid (b=8, kc=kcnt, qt=32), 256 thr = 4 waves; wave owns 32 q-rows,
// iterates its key chunk in 32-key windows. No LDS, no barriers.
__global__ __launch_bounds__(256, 4) void flash_kernel(
    const f16* __restrict__ Qh, const f16* __restrict__ Kh,
    const f16* __restrict__ Vth, float* __restrict__ Opart,
    float* __restrict__ Ml, int kcnt, int kch)
{
    const int lane = threadIdx.x & 63;
    const int wid = threadIdx.x >> 6;
    const int b = blockIdx.x, kc = blockIdx.y, qt = blockIdx.z;
    const int q0 = qt * 128 + wid * 32;
    const int l15 = lane & 15, g = lane >> 4;

    // Q B-frags (col q = l15, k-dims g*8..g*8+7), 2 q-subtiles
    const f16* qp = Qh + ((size_t)b * N_ + q0 + l15) * D_ + g * 8;
    const f16x8 qf0 = *(const f16x8*)qp;
    const f16x8 qf1 = *(const f16x8*)(qp + (size_t)16 * D_);

    // K A-frag base (row key = l15, dims g*8); V^T A-frag base (row d = l15)
    const f16* kp = Kh + ((size_t)b * N_ + (size_t)kc * kch + l15) * D_ + g * 8;
    const f16* vp = Vth + ((size_t)b * D_ + l15) * N_ + (size_t)kc * kch + g * 8;

    f32x4 O00 = {0.f, 0.f, 0.f, 0.f};   // [q-subtile s][d-tile dt]
    f32x4 O01 = O00, O10 = O00, O11 = O00;
    float m0 = -3e38f, m1 = -3e38f, l0 = 0.f, l1 = 0.f;
    const int NW = kch >> 5;

    f16x8 kf0 = *(const f16x8*)kp;
    f16x8 kf1 = *(const f16x8*)(kp + (size_t)16 * D_);
    f16x8 vf0 = *(const f16x8*)vp;
    f16x8 vf1 = *(const f16x8*)(vp + (size_t)16 * N_);

    for (int w = 0; w < NW; ++w) {
        // prefetch next window (clamped; redundant loads on last iter)
        const int wn = (w + 1 < NW) ? (w + 1) : w;
        const f16* kpn = kp + (size_t)wn * 32 * D_;
        const f16* vpn = vp + (size_t)wn * 32;
        const f16x8 kn0 = *(const f16x8*)kpn;
        const f16x8 kn1 = *(const f16x8*)(kpn + (size_t)16 * D_);
        const f16x8 vn0 = *(const f16x8*)vpn;
        const f16x8 vn1 = *(const f16x8*)(vpn + (size_t)16 * N_);

        // S^T tiles: rows = keys (t*16 + 4g + r), cols = q
        const f32x4 z = {0.f, 0.f, 0.f, 0.f};
        f32x4 s00 = __builtin_amdgcn_mfma_f32_16x16x32_f16(kf0, qf0, z, 0, 0, 0);
        f32x4 s01 = __builtin_amdgcn_mfma_f32_16x16x32_f16(kf1, qf0, z, 0, 0, 0);
        f32x4 s10 = __builtin_amdgcn_mfma_f32_16x16x32_f16(kf0, qf1, z, 0, 0, 0);
        f32x4 s11 = __builtin_amdgcn_mfma_f32_16x16x32_f16(kf1, qf1, z, 0, 0, 0);

        // ---- subtile 0 softmax ----
        union { f16x8 v; h16x2 h[4]; } pb0, pb1;
        {
            float mx = fmaxf(fmaxf(fmaxf(s00[0], s00[1]), fmaxf(s00[2], s00[3])),
                             fmaxf(fmaxf(s01[0], s01[1]), fmaxf(s01[2], s01[3])));
            mx = fmaxf(mx, __shfl_xor(mx, 16));
            mx = fmaxf(mx, __shfl_xor(mx, 32));
            if (__any(mx > m0 + 7.f)) {          // defer-max (T13)
                const float nm = fmaxf(m0, mx);
                const float f = __expf(m0 - nm);
                m0 = nm; l0 *= f;
                #pragma unroll
                for (int r = 0; r < 4; ++r) { O00[r] *= f; O01[r] *= f; }
            }
            const float p0 = __expf(s00[0] - m0), p1 = __expf(s00[1] - m0);
            const float p2 = __expf(s00[2] - m0), p3 = __expf(s00[3] - m0);
            const float p4 = __expf(s01[0] - m0), p5 = __expf(s01[1] - m0);
            const float p6 = __expf(s01[2] - m0), p7 = __expf(s01[3] - m0);
            l0 += ((p0 + p1) + (p2 + p3)) + ((p4 + p5) + (p6 + p7));
            pb0.h[0] = __builtin_amdgcn_cvt_pkrtz(p0, p1);
            pb0.h[1] = __builtin_amdgcn_cvt_pkrtz(p2, p3);
            pb0.h[2] = __builtin_amdgcn_cvt_pkrtz(p4, p5);
            pb0.h[3] = __builtin_amdgcn_cvt_pkrtz(p6, p7);
        }
        // ---- subtile 1 softmax ----
        {
            float mx = fmaxf(fmaxf(fmaxf(s10[0], s10[1]), fmaxf(s10[2], s10[3])),
                             fmaxf(fmaxf(s11[0], s11[1]), fmaxf(s11[2], s11[3])));
            mx = fmaxf(mx, __shfl_xor(mx, 16));
            mx = fmaxf(mx, __shfl_xor(mx, 32));
            if (__any(mx > m1 + 7.f)) {
                const float nm = fmaxf(m1, mx);
                const float f = __expf(m1 - nm);
                m1 = nm; l1 *= f;
                #pragma unroll
                for (int r = 0; r < 4; ++r) { O10[r] *= f; O11[r] *= f; }
            }
            const float p0 = __expf(s10[0] - m1), p1 = __expf(s10[1] - m1);
            const float p2 = __expf(s10[2] - m1), p3 = __expf(s10[3] - m1);
            const float p4 = __expf(s11[0] - m1), p5 = __expf(s11[1] - m1);
            const float p6 = __expf(s11[2] - m1), p7 = __expf(s11[3] - m1);
            l1 += ((p0 + p1) + (p2 + p3)) + ((p4 + p5) + (p6 + p7));
            pb1.h[0] = __builtin_amdgcn_cvt_pkrtz(p0, p1);
            pb1.h[1] = __builtin_amdgcn_cvt_pkrtz(p2, p3);
            pb1.h[2] = __builtin_amdgcn_cvt_pkrtz(p4, p5);
            pb1.h[3] = __builtin_amdgcn_cvt_pkrtz(p6, p7);
        }

        // PV: O^T += V^T(dt) . P(s)   (V columns pre-permuted to match slots)
        O00 = __builtin_amdgcn_mfma_f32_16x16x32_f16(vf0, pb0.v, O00, 0, 0, 0);
        O01 = __builtin_amdgcn_mfma_f32_16x16x32_f16(vf1, pb0.v, O01, 0, 0, 0);
        O10 = __builtin_amdgcn_mfma_f32_16x16x32_f16(vf0, pb1.v, O10, 0, 0, 0);
        O11 = __builtin_amdgcn_mfma_f32_16x16x32_f16(vf1, pb1.v, O11, 0, 0, 0);

        kf0 = kn0; kf1 = kn1; vf0 = vn0; vf1 = vn1;
    }

    // deferred cross-group l reduction (q replicated over 4 lane-groups)
    l0 += __shfl_xor(l0, 16); l0 += __shfl_xor(l0, 32);
    l1 += __shfl_xor(l1, 16); l1 += __shfl_xor(l1, 32);

    // O^T store: Opart[b][kc][d][n], d = dt*16 + 4g + r, n = q0 + s*16 + l15
    float* ob = Opart + (size_t)(b * kcnt + kc) * D_ * N_ + q0 + l15;
    #pragma unroll
    for (int r = 0; r < 4; ++r) {
        ob[(size_t)(g * 4 + r) * N_]           = O00[r];
        ob[(size_t)(16 + g * 4 + r) * N_]      = O01[r];
        ob[(size_t)(g * 4 + r) * N_ + 16]      = O10[r];
        ob[(size_t)(16 + g * 4 + r) * N_ + 16] = O11[r];
    }
    if (lane < 16) {
        float2* mp = (float2*)(Ml + ((size_t)(b * kcnt + kc) * N_ + q0 + l15) * 2);
        mp[0]  = make_float2(m0, l0);
        mp[16] = make_float2(m1, l1);
    }
}

// ---- kernel 3: merge partials + Wo projection + residual ---------------
__global__ __launch_bounds__(256) void merge_proj_kernel(
    const float* __restrict__ Opart, const float* __restrict__ Ml,
    const float* __restrict__ wo, const float* __restrict__ gamma,
    const float* __restrict__ x, float* __restrict__ out, int kcnt)
{
    __shared__ float oc[64][33];
    __shared__ float wot[32][260];
    const int tid = threadIdx.x;
    const int n0 = blockIdx.x * 64, b = blockIdx.y;

    for (int i = tid; i < 256 * 32; i += 256) {
        const int c = i >> 5, d = i & 31;
        wot[d][c] = wo[i];
    }

    const int nl = tid & 63;
    const int n = n0 + nl;
    const int grp = tid >> 6;

    {
        const int d0 = grp * 8;
        float mstar = -3e38f;
        for (int c8 = 0; c8 < kcnt; ++c8) {
            const float2 ml = *(const float2*)(Ml + (((size_t)b * kcnt + c8) * N_ + n) * 2);
            mstar = fmaxf(mstar, ml.x);
        }
        float acc[8];
        #pragma unroll
        for (int j = 0; j < 8; ++j) acc[j] = 0.f;
        float lstar = 0.f;
        for (int c8 = 0; c8 < kcnt; ++c8) {
            const float2 ml = *(const float2*)(Ml + (((size_t)b * kcnt + c8) * N_ + n) * 2);
            const float wgt = __expf(ml.x - mstar);
            lstar += wgt * ml.y;
            const float* op = Opart + (((size_t)b * kcnt + c8) * D_ + d0) * N_ + n;
            #pragma unroll
            for (int j = 0; j < 8; ++j) acc[j] += wgt * op[(size_t)j * N_];
        }
        const float inv = 1.0f / lstar;
        #pragma unroll
        for (int j = 0; j < 8; ++j) oc[nl][d0 + j] = acc[j] * inv;
    }
    __syncthreads();

    const float gmv = gamma[0];
    const float* xb = x + (size_t)b * C_ * N_ + n;
    float* ob = out + (size_t)b * C_ * N_ + n;
    for (int cg = 0; cg < 8; ++cg) {
        const int c0 = grp * 64 + cg * 8;
        float acc8[8];
        #pragma unroll
        for (int j = 0; j < 8; ++j) acc8[j] = 0.f;
        for (int d = 0; d < 32; ++d) {
            const float ov = oc[nl][d];
            const float4 w0 = *(const float4*)&wot[d][c0];
            const float4 w1 = *(const float4*)&wot[d][c0 + 4];
            acc8[0] += w0.x * ov; acc8[1] += w0.y * ov; acc8[2] += w0.z * ov; acc8[3] += w0.w * ov;
            acc8[4] += w1.x * ov; acc8[5] += w1.y * ov; acc8[6] += w1.z * ov; acc8[7] += w1.w * ov;
        }
        #pragma unroll
        for (int j = 0; j < 8; ++j) {
            const size_t off = (size_t)(c0 + j) * N_;
            ob[off] = gmv * acc8[j] + xb[off];
        }
    }
}

extern "C" void kernel_launch(void* const* d_in, const int* in_sizes, int n_in,
                              void* d_out, int out_size, void* d_ws, size_t ws_size,
                              hipStream_t stream) {
    const float* x  = (const float*)d_in[0];
    const float* wq = (const float*)d_in[1];
    const float* wk = (const float*)d_in[2];
    const float* wv = (const float*)d_in[3];
    const float* wo = (const float*)d_in[4];
    const float* gm = (const float*)d_in[5];
    float* out = (float*)d_out;

    int kcnt = 4;
    while (kcnt > 1) {
        const size_t need = 3 * (size_t)B_ * N_ * D_ * 2
                          + (size_t)B_ * kcnt * N_ * D_ * 4
                          + (size_t)B_ * kcnt * N_ * 2 * 4;
        if (need <= ws_size) break;
        kcnt >>= 1;
    }
    const int kch = N_ / kcnt;

    f16* Qb  = (f16*)d_ws;
    f16* Kb  = Qb + (size_t)B_ * N_ * D_;
    f16* Vtb = Kb + (size_t)B_ * N_ * D_;
    float* Opart = (float*)(Vtb + (size_t)B_ * N_ * D_);
    float* Mlb   = Opart + (size_t)B_ * kcnt * N_ * D_;

    qkv_kernel<<<dim3(64, 3, B_), 256, 0, stream>>>(x, wq, wk, wv, Qb, Kb, Vtb);
    flash_kernel<<<dim3(B_, kcnt, N_ / 128), 256, 0, stream>>>(Qb, Kb, Vtb, Opart, Mlb,
                                                               kcnt, kch);
    merge_proj_kernel<<<dim3(64, B_), 256, 0, stream>>>(Opart, Mlb, wo, gm, x, out, kcnt);
}